// Round 11
// baseline (663.445 us; speedup 1.0000x reference)
//
#include <hip/hip_runtime.h>
#include <hip/hip_cooperative_groups.h>

// incepLayer, float32 in/out. out = concat([h, f1, f2, f3]); f_k are alpha-
// mixes of P^k h, P = weighted segment_sum over edges, e = d[src]*d[dst].
//
// R11 = the banked 212.4 us R1.5 kernel (scalar-bucket gather, 8-wide unroll,
// bf16 rows, CAP=64 buckets), fused into ONE cooperative launch:
//   phase0 zero counts | phase1 build buckets + cvt h->bf16 | phase2 agg1 |
//   phase3 agg2 | phase4 agg3+epilogue, grid.sync() between phases.
// Rationale (R10 ledger): chunked family falsified 5x — gather service is
// pinned ~3.6-3.9 TB/s regardless of residency/issue shape (HW random-line
// cap); the only deterministic headroom left is dispatch overhead (~25-40 us
// across 6 dispatches). Per-phase code is byte-equivalent to the verified
// R1.5 kernels; numerics unchanged (f16 weights, bf16 rows, f32 acc).
// grid=1024x256 with __launch_bounds__(256,4) -> guaranteed co-resident.

namespace cg = cooperative_groups;

#define NN  40000
#define NE  640000
#define CAP 64   // in-degree ~ Poisson(16); P(>64) ~ 1e-17

typedef unsigned int uint;
typedef unsigned short ushort;

__device__ inline ushort f2h(float f) {
    _Float16 h = (_Float16)f;
    return *(ushort*)&h;
}
__device__ inline float h2f(ushort u) {
    _Float16 h = *(_Float16*)&u;
    return (float)h;
}
__device__ inline ushort f2bf(float f) {  // round-to-nearest-even
    uint x = __float_as_uint(f);
    x += 0x7fffu + ((x >> 16) & 1u);
    return (ushort)(x >> 16);
}
__device__ inline uint pack_bf2(float x, float y) {
    return ((uint)f2bf(y) << 16) | (uint)f2bf(x);
}
__device__ inline float bflo(uint u) { return __uint_as_float(u << 16); }
__device__ inline float bfhi(uint u) { return __uint_as_float(u & 0xffff0000u); }

// ---- verified R1.5 gather: scalar bucket reads, 8 loads in flight ----------
__device__ inline float2 gather_node(
    const uint* __restrict__ feat,   // bf16 rows, 64 words per row
    const int* __restrict__ counts, const uint* __restrict__ buck,
    int v, int lane) {
    int vs = __builtin_amdgcn_readfirstlane(v);
    int cnt = counts[vs];
    if (cnt > CAP) cnt = CAP;
    const uint* brow = buck + (size_t)vs * CAP;

    float ax = 0.f, ay = 0.f, bx = 0.f, by = 0.f;
    float cx = 0.f, cy = 0.f, dx = 0.f, dy = 0.f;
    for (int j = 0; j < cnt; j += 8) {
        uint uu[8];
#pragma unroll
        for (int k = 0; k < 8; ++k) uu[k] = brow[j + k];   // scalar loads
        float wj[8]; int sj[8];
#pragma unroll
        for (int k = 0; k < 8; ++k) {
            bool ok = (j + k) < cnt;    // tail slots hold poison
            wj[k] = ok ? h2f((ushort)(uu[k] >> 16)) : 0.f;
            sj[k] = ok ? (int)(uu[k] & 0xffffu) : 0;
        }
        uint fj[8];
#pragma unroll
        for (int k = 0; k < 8; ++k)
            fj[k] = feat[(size_t)sj[k] * 64 + lane];       // 8 in flight
#pragma unroll
        for (int k = 0; k < 8; k += 4) {
            ax = fmaf(wj[k + 0], bflo(fj[k + 0]), ax);
            ay = fmaf(wj[k + 0], bfhi(fj[k + 0]), ay);
            bx = fmaf(wj[k + 1], bflo(fj[k + 1]), bx);
            by = fmaf(wj[k + 1], bfhi(fj[k + 1]), by);
            cx = fmaf(wj[k + 2], bflo(fj[k + 2]), cx);
            cy = fmaf(wj[k + 2], bfhi(fj[k + 2]), cy);
            dx = fmaf(wj[k + 3], bflo(fj[k + 3]), dx);
            dy = fmaf(wj[k + 3], bfhi(fj[k + 3]), dy);
        }
    }
    return make_float2((ax + bx) + (cx + dx), (ay + by) + (cy + dy));
}

__global__ __launch_bounds__(256, 4) void mega_k(
    const float* __restrict__ h, const float* __restrict__ deg,
    const float* __restrict__ alphas,
    const int* __restrict__ src, const int* __restrict__ dst,
    int* __restrict__ counts, uint* __restrict__ buck,
    uint* __restrict__ hb, uint* __restrict__ p1b, uint* __restrict__ p2b,
    float* __restrict__ out) {
    cg::grid_group grid = cg::this_grid();
    const int nthr = (int)(gridDim.x * 256);
    const int tid  = (int)(blockIdx.x * 256 + threadIdx.x);
    const int lane = tid & 63;
    const int wid  = tid >> 6;
    const int wstr = nthr >> 6;

    // ---- phase 0: zero counts ---------------------------------------------
    for (int i = tid; i < NN; i += nthr) counts[i] = 0;
    grid.sync();

    // ---- phase 1: build buckets + cvt h -> bf16 rows ----------------------
    for (int e = tid; e < NE; e += nthr) {
        int s = src[e];
        int v = dst[e];
        int slot = atomicAdd(&counts[v], 1);
        if (slot < CAP) {
            float w = deg[s] * deg[v];
            buck[v * CAP + slot] = ((uint)f2h(w) << 16) | (uint)s;
        }
    }
    for (int i = tid; i < NN * 64; i += nthr) {
        float2 f = *(const float2*)(h + (size_t)i * 2);
        hb[i] = pack_bf2(f.x, f.y);
    }
    grid.sync();

    // ---- phase 2: agg1  hb -> p1b -----------------------------------------
    for (int v = wid; v < NN; v += wstr) {
        float2 a = gather_node(hb, counts, buck, v, lane);
        p1b[(size_t)v * 64 + lane] = pack_bf2(a.x, a.y);
    }
    grid.sync();

    // ---- phase 3: agg2  p1b -> p2b ----------------------------------------
    for (int v = wid; v < NN; v += wstr) {
        float2 a = gather_node(p1b, counts, buck, v, lane);
        p2b[(size_t)v * 64 + lane] = pack_bf2(a.x, a.y);
    }
    grid.sync();

    // ---- phase 4: agg3 + alpha-combine + write all 4 sections -------------
    float a0 = alphas[0], a1 = alphas[1], a2 = alphas[2];
    float a3 = alphas[3], a4 = alphas[4], a5 = alphas[5];
    float c1p = a0, c1h = 1.f - a0;
    float c2pp = a2 * a1;
    float c2p  = a2 * (1.f - a1) + (1.f - a2) * a1;
    float c2h  = (1.f - a2) * (1.f - a1);
    float s2pp = a4 * a3;
    float s2p  = a4 * (1.f - a3) + (1.f - a4) * a3;
    float s2h  = (1.f - a4) * (1.f - a3);
    float c3ppp = a5 * s2pp;
    float c3pp  = a5 * s2p + (1.f - a5) * s2pp;
    float c3p   = a5 * s2h + (1.f - a5) * s2p;
    float c3h   = (1.f - a5) * s2h;

    for (int v = wid; v < NN; v += wstr) {
        float2 p3 = gather_node(p2b, counts, buck, v, lane);
        int i2 = lane * 2;
        float2 hf = *(const float2*)(h + (size_t)v * 128 + i2);
        uint u1 = p1b[(size_t)v * 64 + lane];
        uint u2 = p2b[(size_t)v * 64 + lane];
        float q1x = bflo(u1), q1y = bfhi(u1);
        float q2x = bflo(u2), q2y = bfhi(u2);

        float2 r1, r2, r3;
        r1.x = c1p * q1x + c1h * hf.x;
        r1.y = c1p * q1y + c1h * hf.y;
        r2.x = c2pp * q2x + c2p * q1x + c2h * hf.x;
        r2.y = c2pp * q2y + c2p * q1y + c2h * hf.y;
        r3.x = c3ppp * p3.x + c3pp * q2x + c3p * q1x + c3h * hf.x;
        r3.y = c3ppp * p3.y + c3pp * q2y + c3p * q1y + c3h * hf.y;

        float* o = out + (size_t)v * 512;
        *(float2*)(o + i2)       = hf;
        *(float2*)(o + 128 + i2) = r1;
        *(float2*)(o + 256 + i2) = r2;
        *(float2*)(o + 384 + i2) = r3;
    }
}

extern "C" void kernel_launch(void* const* d_in, const int* in_sizes, int n_in,
                              void* d_out, int out_size, void* d_ws, size_t ws_size,
                              hipStream_t stream) {
    const float* h      = (const float*)d_in[0];
    const float* deg    = (const float*)d_in[1];
    const float* alphas = (const float*)d_in[2];
    const int*   src    = (const int*)d_in[3];
    const int*   dst    = (const int*)d_in[4];
    float* out = (float*)d_out;

    // ws layout (bytes): counts 160,000 | buck 10,240,000 |
    //                    hb 10,240,000 | p1b 10,240,000 | p2b 10,240,000
    char* ws = (char*)d_ws;
    int*  counts = (int*)(ws + 0);
    uint* buck   = (uint*)(ws + 160000);
    uint* hb     = (uint*)(ws + 10400000);
    uint* p1b    = (uint*)(ws + 20640000);
    uint* p2b    = (uint*)(ws + 30880000);

    void* args[] = {
        (void*)&h, (void*)&deg, (void*)&alphas, (void*)&src, (void*)&dst,
        (void*)&counts, (void*)&buck, (void*)&hb, (void*)&p1b, (void*)&p2b,
        (void*)&out
    };
    (void)hipLaunchCooperativeKernel((const void*)mega_k, dim3(1024),
                                     dim3(256), args, 0, stream);
}